// Round 6
// baseline (587.876 us; speedup 1.0000x reference)
//
#include <hip/hip_runtime.h>

typedef unsigned short u16;
typedef unsigned int   u32;
typedef __attribute__((ext_vector_type(8))) short short8v;
typedef __attribute__((ext_vector_type(8))) unsigned short us8;
typedef __attribute__((ext_vector_type(4))) float f32x4;
typedef __attribute__((ext_vector_type(2))) unsigned int u32x2;

static __device__ __forceinline__ float bf2f(u16 u){ union{u32 i; float f;} v; v.i=(u32)u<<16; return v.f; }
static __device__ __forceinline__ u16 f2bf(float f){ union{float f; u32 i;} u; u.f=f; u32 r=u.i+0x7FFFu+((u.i>>16)&1u); return (u16)(r>>16); }

static __device__ __forceinline__ float ld1(const void* p, size_t i, int f32){
  return f32 ? ((const float*)p)[i] : bf2f(((const u16*)p)[i]);
}
static __device__ __forceinline__ float4 ld4(const void* p, size_t i, int f32){
  if (f32) return *((const float4*)((const float*)p + i));
  ushort4 v = *((const ushort4*)((const u16*)p + i));
  return make_float4(bf2f(v.x), bf2f(v.y), bf2f(v.z), bf2f(v.w));
}
static __device__ __forceinline__ void st1(void* p, size_t i, float v, int f32){
  if (f32) ((float*)p)[i] = v; else ((u16*)p)[i] = f2bf(v);
}
static __device__ __forceinline__ int lde(const int* ei, size_t i, int i64){
  return i64 ? ei[2*i] : ei[i];
}
static __device__ __forceinline__ int clampi(int v, int lo, int hi){ return v<lo?lo:(v>hi?hi:v); }

// ---------------- runtime dtype detection ----------------
__global__ void detect_kernel(const u32* __restrict__ x, const int* __restrict__ ei,
                              int* __restrict__ flags){
  __shared__ int cnt[2];
  int t = threadIdx.x;
  if (t < 2) cnt[t] = 0;
  __syncthreads();
  int good = 0;
  for (int i = t; i < 4096; i += 256){
    u32 e = (x[i] >> 7) & 0xFFu;
    if (e >= 90u && e <= 150u) good++;
  }
  atomicAdd(&cnt[0], good);
  int nzodd = 0;
  for (int i = t; i < 2048; i += 256){
    if (ei[2*i+1] != 0) nzodd++;
  }
  atomicAdd(&cnt[1], nzodd);
  __syncthreads();
  if (t == 0){
    flags[0] = (cnt[0] < 2867) ? 1 : 0;
    flags[1] = (cnt[1] == 0) ? 1 : 0;
  }
}

// ---------------- CSR build (stores SRC row BYTE offset: src*512) ----------------
__global__ void count_kernel(const int* __restrict__ ei, int E, int N,
                             int* __restrict__ deg, const int* __restrict__ flags){
  int i64 = flags[1];
  int i = blockIdx.x*blockDim.x + threadIdx.x;
  int Et = E + N;
  if (i < Et){
    int d = (i < E) ? clampi(lde(ei, (size_t)E + i, i64), 0, N-1) : (i - E);
    atomicAdd(&deg[d], 1);
  }
}

__global__ __launch_bounds__(256) void scan1_kernel(const int* __restrict__ deg,
    int* __restrict__ offs, int* __restrict__ bsum, int N){
  __shared__ int sm[256];
  int t = threadIdx.x;
  int i = blockIdx.x*256 + t;
  int v = (i < N) ? deg[i] : 0;
  sm[t] = v; __syncthreads();
  #pragma unroll
  for (int off = 1; off < 256; off <<= 1){
    int u = (t >= off) ? sm[t-off] : 0;
    __syncthreads();
    sm[t] += u;
    __syncthreads();
  }
  if (i < N) offs[i] = sm[t] - v;
  if (t == 255) bsum[blockIdx.x] = sm[255];
}

__global__ __launch_bounds__(1024) void scan2_kernel(const int* __restrict__ bsum,
    int* __restrict__ bpre, int NB){
  __shared__ int sm[1024];
  int t = threadIdx.x;
  int v = (t < NB) ? bsum[t] : 0;
  sm[t] = v; __syncthreads();
  #pragma unroll
  for (int off = 1; off < 1024; off <<= 1){
    int u = (t >= off) ? sm[t-off] : 0;
    __syncthreads();
    sm[t] += u;
    __syncthreads();
  }
  if (t < NB) bpre[t] = sm[t] - v;
  if (t == 1023) bpre[NB] = sm[1023];
}

__global__ __launch_bounds__(256) void scan3_kernel(int* __restrict__ offs,
    int* __restrict__ cursor, const int* __restrict__ bpre, int N, int NB){
  int i = blockIdx.x*256 + threadIdx.x;
  if (i < N){
    int v = offs[i] + bpre[blockIdx.x];
    offs[i] = v; cursor[i] = v;
  }
  if (i == 0) offs[N] = bpre[NB];
}

__global__ void scatter_kernel(const int* __restrict__ ei, int E, int N,
    int* __restrict__ cursor, int* __restrict__ csr_boff, const int* __restrict__ flags){
  int i64 = flags[1];
  int i = blockIdx.x*blockDim.x + threadIdx.x;
  int Et = E + N;
  if (i < Et){
    int s, d;
    if (i < E){
      s = clampi(lde(ei, i, i64), 0, N-1);
      d = clampi(lde(ei, (size_t)E + i, i64), 0, N-1);
    } else { s = i - E; d = s; }
    int p = atomicAdd(&cursor[d], 1);
    csr_boff[p] = s * 512;          // byte offset of h row (256 ch * 2B)
  }
}

// ---------------- MFMA GEMM: C[M,256] = A[M,256] @ B[256,256], bf16 mfma, f32 acc ----------------
__global__ __launch_bounds__(256) void gemm_mfma(const void* __restrict__ A,
    const void* __restrict__ B, u16* __restrict__ C, int M, int aIsInput,
    const int* __restrict__ flags){
  int af32 = aIsInput ? flags[0] : 0;
  int bf32 = flags[0];
  __shared__ __align__(16) u16 As[128][40];
  __shared__ __align__(16) u16 Bt[64][264];
  int tid = threadIdx.x;
  int col0 = blockIdx.x * 64;
  int row0 = blockIdx.y * 128;

  { // stage whole B-panel transposed: thread t = row k of B
    int k = tid;
    if (bf32){
      const float* Bp = (const float*)B + (size_t)k*256 + col0;
      #pragma unroll
      for (int j = 0; j < 64; j += 4){
        float4 v = *(const float4*)(Bp + j);
        Bt[j+0][k] = f2bf(v.x); Bt[j+1][k] = f2bf(v.y);
        Bt[j+2][k] = f2bf(v.z); Bt[j+3][k] = f2bf(v.w);
      }
    } else {
      const u16* Bp = (const u16*)B + (size_t)k*256 + col0;
      #pragma unroll
      for (int j = 0; j < 64; j += 4){
        ushort4 v = *(const ushort4*)(Bp + j);
        Bt[j+0][k] = v.x; Bt[j+1][k] = v.y; Bt[j+2][k] = v.z; Bt[j+3][k] = v.w;
      }
    }
  }

  int wave = tid >> 6, lane = tid & 63;
  int wm = wave >> 1, wn = wave & 1;
  int l15 = lane & 15, l4 = lane >> 4;
  f32x4 acc[4][2] = {};
  int arow = tid >> 1, akseg = (tid & 1) * 16;

  for (int k0 = 0; k0 < 256; k0 += 32){
    __syncthreads();
    { // stage A rows [row0, row0+128) x [k0, k0+32)
      int gr = row0 + arow;
      us8 p0 = (us8){0,0,0,0,0,0,0,0}, p1 = (us8){0,0,0,0,0,0,0,0};
      if (gr < M){
        if (af32){
          const float* Ap = (const float*)A + (size_t)gr*256 + k0 + akseg;
          float4 a0 = *(const float4*)(Ap+0), a1 = *(const float4*)(Ap+4);
          float4 a2 = *(const float4*)(Ap+8), a3 = *(const float4*)(Ap+12);
          p0 = (us8){f2bf(a0.x),f2bf(a0.y),f2bf(a0.z),f2bf(a0.w),
                     f2bf(a1.x),f2bf(a1.y),f2bf(a1.z),f2bf(a1.w)};
          p1 = (us8){f2bf(a2.x),f2bf(a2.y),f2bf(a2.z),f2bf(a2.w),
                     f2bf(a3.x),f2bf(a3.y),f2bf(a3.z),f2bf(a3.w)};
        } else {
          const u16* Ap = (const u16*)A + (size_t)gr*256 + k0 + akseg;
          p0 = *(const us8*)Ap; p1 = *(const us8*)(Ap+8);
        }
      }
      *(us8*)&As[arow][akseg]   = p0;
      *(us8*)&As[arow][akseg+8] = p1;
    }
    __syncthreads();
    short8v a[4], b[2];
    #pragma unroll
    for (int mi = 0; mi < 4; mi++)
      a[mi] = *(const short8v*)&As[wm*64 + mi*16 + l15][8*l4];
    #pragma unroll
    for (int ni = 0; ni < 2; ni++)
      b[ni] = *(const short8v*)&Bt[wn*32 + ni*16 + l15][k0 + 8*l4];
    #pragma unroll
    for (int mi = 0; mi < 4; mi++)
      #pragma unroll
      for (int ni = 0; ni < 2; ni++)
        acc[mi][ni] = __builtin_amdgcn_mfma_f32_16x16x32_bf16(a[mi], b[ni], acc[mi][ni], 0, 0, 0);
  }

  #pragma unroll
  for (int mi = 0; mi < 4; mi++){
    #pragma unroll
    for (int ni = 0; ni < 2; ni++){
      #pragma unroll
      for (int r = 0; r < 4; r++){
        int row = row0 + wm*64 + mi*16 + l4*4 + r;
        int col = col0 + wn*32 + ni*16 + l15;
        if (row < M) C[(size_t)row*256 + col] = f2bf(acc[mi][ni][r]);
      }
    }
  }
}

// ---------------- per-node attention scores es/ed (4 nodes/block) ----------------
__global__ __launch_bounds__(256) void scores_kernel(const u16* __restrict__ h,
    const void* __restrict__ a_src, const void* __restrict__ a_dst,
    float* __restrict__ es, float* __restrict__ ed, int N, const int* __restrict__ flags){
  int f32 = flags[0];
  int ln = threadIdx.x & 63;
  int n = blockIdx.x*4 + (threadIdx.x >> 6);
  if (n >= N) return;
  int c0 = ln*4, hd = ln >> 4;
  ushort4 hv = *(const ushort4*)&h[(size_t)n*256 + c0];
  float4 s4 = ld4(a_src, c0, f32);
  float4 d4 = ld4(a_dst, c0, f32);
  float ps = bf2f(hv.x)*s4.x + bf2f(hv.y)*s4.y + bf2f(hv.z)*s4.z + bf2f(hv.w)*s4.w;
  float pd = bf2f(hv.x)*d4.x + bf2f(hv.y)*d4.y + bf2f(hv.z)*d4.z + bf2f(hv.w)*d4.w;
  #pragma unroll
  for (int off = 1; off < 16; off <<= 1){
    ps += __shfl_xor(ps, off, 64);
    pd += __shfl_xor(pd, off, 64);
  }
  if ((ln & 15) == 0){ es[(size_t)n*4 + hd] = ps; ed[(size_t)n*4 + hd] = pd; }
}

// ---------------- channel-sliced aggregation: slice = blockIdx & 7 (XCD-pinned) ----------------
// Each wave: one (node, 32-channel slice); 8 edges in flight x 8 lanes (4 ch each).
__global__ __launch_bounds__(256) void agg_kernel(const u16* __restrict__ h,
    const int* __restrict__ csr_boff, const int* __restrict__ offs,
    const float* __restrict__ es, const float* __restrict__ ed, int N,
    const void* __restrict__ bias, void* __restrict__ out, int do_relu, int outIsOutput,
    const int* __restrict__ flags){
  int f32in = flags[0];
  int of32  = outIsOutput ? flags[0] : 0;
  int slice = blockIdx.x & 7;                 // round-robin dispatch -> pinned XCD
  int wv = threadIdx.x >> 6, ln = threadIdx.x & 63;
  int n = (blockIdx.x >> 3) * 4 + wv;
  if (n >= N) return;
  int e8 = ln >> 3;                           // edge subgroup 0..7
  int c8 = ln & 7;                            // channel subgroup (4 ch each)
  int hd4 = (slice >> 1) * 4;                 // head byte offset in es row
  int cbase = slice*32 + c8*4;                // first channel of this lane
  int beg = offs[n], end = offs[n+1];
  float edn = ed[(size_t)n*4 + (slice >> 1)];
  float a0=0.f, a1=0.f, a2=0.f, a3=0.f, ws=0.f;
  const char* hbase = (const char*)h;
  const char* ebase = (const char*)es;
  size_t coff = (size_t)cbase*2;
  #pragma unroll 2
  for (int i = beg; i < end; i += 8){
    int idx = i + e8;
    bool ok = idx < end;
    int boff = __builtin_nontemporal_load(&csr_boff[ok ? idx : beg]);
    float x = *(const float*)(ebase + (boff >> 5) + hd4);
    float t = x + edn; t = (t > 0.f) ? t : 0.2f*t; t = fminf(t, 60.f);
    float w = ok ? __expf(t) : 0.f;
    ushort4 hv = *(const ushort4*)(hbase + boff + coff);
    a0 += w*bf2f(hv.x); a1 += w*bf2f(hv.y);
    a2 += w*bf2f(hv.z); a3 += w*bf2f(hv.w);
    ws += w;
  }
  #pragma unroll
  for (int off = 8; off < 64; off <<= 1){
    a0 += __shfl_xor(a0, off, 64);
    a1 += __shfl_xor(a1, off, 64);
    a2 += __shfl_xor(a2, off, 64);
    a3 += __shfl_xor(a3, off, 64);
    ws += __shfl_xor(ws, off, 64);
  }
  if (e8 == 0){
    float inv = 1.f / (ws + 1e-16f);
    float4 bv = ld4(bias, cbase, f32in);
    float o0 = a0*inv + bv.x, o1 = a1*inv + bv.y;
    float o2 = a2*inv + bv.z, o3 = a3*inv + bv.w;
    if (do_relu){
      o0 = fmaxf(o0, 0.f); o1 = fmaxf(o1, 0.f);
      o2 = fmaxf(o2, 0.f); o3 = fmaxf(o3, 0.f);
    }
    if (of32){
      f32x4 ov = (f32x4){o0, o1, o2, o3};
      __builtin_nontemporal_store(ov, (f32x4*)((float*)out + (size_t)n*256 + cbase));
    } else {
      u32x2 uv;
      uv.x = (u32)f2bf(o0) | ((u32)f2bf(o1) << 16);
      uv.y = (u32)f2bf(o2) | ((u32)f2bf(o3) << 16);
      __builtin_nontemporal_store(uv, (u32x2*)((u16*)out + (size_t)n*256 + cbase));
    }
  }
}

// ---------------- query part of classifier ----------------
__global__ void qpart_kernel(const void* __restrict__ query, const void* __restrict__ Wc,
    const void* __restrict__ bc, float* __restrict__ qp, int Q, const int* __restrict__ flags){
  int f32 = flags[0];
  int q = threadIdx.x >> 5, ln = threadIdx.x & 31;
  if (q >= Q) return;
  float s = 0.f;
  for (int j = ln; j < 256; j += 32) s += ld1(query, q*256 + j, f32) * ld1(Wc, j, f32);
  #pragma unroll
  for (int off = 16; off; off >>= 1) s += __shfl_down(s, off, 32);
  if (ln == 0) qp[q] = s + ld1(bc, 0, f32);
}

// ---------------- node scores ----------------
__global__ __launch_bounds__(256) void nscore_kernel(const void* __restrict__ dout,
    const void* __restrict__ Wc, const float* __restrict__ qp, int N, int Q,
    const int* __restrict__ flags){
  int f32 = flags[0];
  int wv = threadIdx.x >> 6, ln = threadIdx.x & 63;
  int n = blockIdx.x * 4 + wv;
  if (n >= N) return;
  float4 e4 = ld4(dout, (size_t)n*256 + ln*4, f32);
  float4 w4 = ld4(Wc, 256 + ln*4, f32);
  float v = e4.x*w4.x + e4.y*w4.y + e4.z*w4.z + e4.w*w4.w;
  #pragma unroll
  for (int off = 32; off; off >>= 1) v += __shfl_down(v, off, 64);
  v = __shfl(v, 0, 64);
  if (ln < Q) st1((void*)dout, (size_t)N*256 + (size_t)ln*N + n, qp[ln] + v, f32);
}

extern "C" void kernel_launch(void* const* d_in, const int* in_sizes, int n_in,
                              void* d_out, int out_size, void* d_ws, size_t ws_size,
                              hipStream_t stream){
  const void* x     = d_in[0];
  const int*  ei    = (const int*)d_in[1];
  const void* query = d_in[2];
  const void* W1    = d_in[3];
  const void* as1   = d_in[4];
  const void* ad1   = d_in[5];
  const void* b1    = d_in[6];
  const void* W2    = d_in[7];
  const void* as2   = d_in[8];
  const void* ad2   = d_in[9];
  const void* b2    = d_in[10];
  const void* Wc    = d_in[11];
  const void* bc    = d_in[12];

  int N = in_sizes[0] / 256;
  int E = in_sizes[1] / 2;
  int Q = in_sizes[2] / 256;
  int Et = E + N;
  int NB = (N + 255) / 256;

  char* p = (char*)d_ws;
  auto alloc = [&](size_t bytes)->char*{
    char* r = p; p += (bytes + 255) & ~(size_t)255; return r;
  };
  int*  flags    = (int*) alloc(256);
  u16*  bufA     = (u16*) alloc((size_t)N*256*2);
  u16*  bufB     = (u16*) alloc((size_t)N*256*2);
  float* es      = (float*)alloc((size_t)N*4*4);
  float* ed      = (float*)alloc((size_t)N*4*4);
  int*  deg      = (int*)  alloc((size_t)N*4);
  int*  offs     = (int*)  alloc((size_t)(N+1)*4);
  int*  cursor   = (int*)  alloc((size_t)N*4);
  int*  csr_boff = (int*)  alloc((size_t)Et*4);
  int*  bsum     = (int*)  alloc((size_t)(NB+1)*4);
  int*  bpre     = (int*)  alloc((size_t)(NB+1)*4);
  float* qp      = (float*)alloc(64*4);

  const int thr = 256;
  detect_kernel<<<1, 256, 0, stream>>>((const u32*)x, ei, flags);

  hipMemsetAsync(deg, 0, (size_t)N*4, stream);
  count_kernel  <<<(Et + thr-1)/thr, thr, 0, stream>>>(ei, E, N, deg, flags);
  scan1_kernel  <<<NB, 256, 0, stream>>>(deg, offs, bsum, N);
  scan2_kernel  <<<1, 1024, 0, stream>>>(bsum, bpre, NB);
  scan3_kernel  <<<NB, 256, 0, stream>>>(offs, cursor, bpre, N, NB);
  scatter_kernel<<<(Et + thr-1)/thr, thr, 0, stream>>>(ei, E, N, cursor, csr_boff, flags);

  dim3 ggrid(4, (N + 127)/128);
  dim3 ngrid((N + 3)/4);
  dim3 agrid(8 * ((N + 3)/4));    // slice-major: blockIdx & 7 = channel slice (XCD)
  // ---- layer 1 ----
  gemm_mfma    <<<ggrid, 256, 0, stream>>>(x, W1, bufA, N, 1, flags);
  scores_kernel<<<ngrid, 256, 0, stream>>>(bufA, as1, ad1, es, ed, N, flags);
  agg_kernel   <<<agrid, 256, 0, stream>>>(bufA, csr_boff, offs, es, ed, N, b1, bufB, 1, 0, flags);
  // ---- layer 2 ----
  gemm_mfma    <<<ggrid, 256, 0, stream>>>(bufB, W2, bufA, N, 0, flags);
  scores_kernel<<<ngrid, 256, 0, stream>>>(bufA, as2, ad2, es, ed, N, flags);
  agg_kernel   <<<agrid, 256, 0, stream>>>(bufA, csr_boff, offs, es, ed, N, b2, d_out, 0, 1, flags);
  // ---- classifier head ----
  qpart_kernel <<<1, 256, 0, stream>>>(query, Wc, bc, qp, Q, flags);
  nscore_kernel<<<ngrid, 256, 0, stream>>>(d_out, Wc, qp, N, Q, flags);
}

// Round 7
// 384.709 us; speedup vs baseline: 1.5281x; 1.5281x over previous
//
#include <hip/hip_runtime.h>

typedef unsigned short u16;
typedef unsigned int   u32;
typedef __attribute__((ext_vector_type(8))) short short8v;
typedef __attribute__((ext_vector_type(8))) unsigned short us8;
typedef __attribute__((ext_vector_type(4))) float f32x4;

static __device__ __forceinline__ float bf2f(u16 u){ union{u32 i; float f;} v; v.i=(u32)u<<16; return v.f; }
static __device__ __forceinline__ u16 f2bf(float f){ union{float f; u32 i;} u; u.f=f; u32 r=u.i+0x7FFFu+((u.i>>16)&1u); return (u16)(r>>16); }

static __device__ __forceinline__ float ld1(const void* p, size_t i, int f32){
  return f32 ? ((const float*)p)[i] : bf2f(((const u16*)p)[i]);
}
static __device__ __forceinline__ float4 ld4(const void* p, size_t i, int f32){
  if (f32) return *((const float4*)((const float*)p + i));
  ushort4 v = *((const ushort4*)((const u16*)p + i));
  return make_float4(bf2f(v.x), bf2f(v.y), bf2f(v.z), bf2f(v.w));
}
static __device__ __forceinline__ void st4(void* p, size_t i, float4 v, int f32){
  if (f32) *((float4*)((float*)p + i)) = v;
  else { ushort4 o; o.x=f2bf(v.x); o.y=f2bf(v.y); o.z=f2bf(v.z); o.w=f2bf(v.w); *((ushort4*)((u16*)p + i)) = o; }
}
static __device__ __forceinline__ void st1(void* p, size_t i, float v, int f32){
  if (f32) ((float*)p)[i] = v; else ((u16*)p)[i] = f2bf(v);
}
static __device__ __forceinline__ int lde(const int* ei, size_t i, int i64){
  return i64 ? ei[2*i] : ei[i];
}
static __device__ __forceinline__ int clampi(int v, int lo, int hi){ return v<lo?lo:(v>hi?hi:v); }

// ---------------- runtime dtype detection ----------------
__global__ void detect_kernel(const u32* __restrict__ x, const int* __restrict__ ei,
                              int* __restrict__ flags){
  __shared__ int cnt[2];
  int t = threadIdx.x;
  if (t < 2) cnt[t] = 0;
  __syncthreads();
  int good = 0;
  for (int i = t; i < 4096; i += 256){
    u32 e = (x[i] >> 7) & 0xFFu;
    if (e >= 90u && e <= 150u) good++;
  }
  atomicAdd(&cnt[0], good);
  int nzodd = 0;
  for (int i = t; i < 2048; i += 256){
    if (ei[2*i+1] != 0) nzodd++;
  }
  atomicAdd(&cnt[1], nzodd);
  __syncthreads();
  if (t == 0){
    flags[0] = (cnt[0] < 2867) ? 1 : 0;
    flags[1] = (cnt[1] == 0) ? 1 : 0;
  }
}

// ---------------- CSR build (stores src node id) ----------------
__global__ void count_kernel(const int* __restrict__ ei, int E, int N,
                             int* __restrict__ deg, const int* __restrict__ flags){
  int i64 = flags[1];
  int i = blockIdx.x*blockDim.x + threadIdx.x;
  int Et = E + N;
  if (i < Et){
    int d = (i < E) ? clampi(lde(ei, (size_t)E + i, i64), 0, N-1) : (i - E);
    atomicAdd(&deg[d], 1);
  }
}

__global__ __launch_bounds__(256) void scan1_kernel(const int* __restrict__ deg,
    int* __restrict__ offs, int* __restrict__ bsum, int N){
  __shared__ int sm[256];
  int t = threadIdx.x;
  int i = blockIdx.x*256 + t;
  int v = (i < N) ? deg[i] : 0;
  sm[t] = v; __syncthreads();
  #pragma unroll
  for (int off = 1; off < 256; off <<= 1){
    int u = (t >= off) ? sm[t-off] : 0;
    __syncthreads();
    sm[t] += u;
    __syncthreads();
  }
  if (i < N) offs[i] = sm[t] - v;
  if (t == 255) bsum[blockIdx.x] = sm[255];
}

__global__ __launch_bounds__(1024) void scan2_kernel(const int* __restrict__ bsum,
    int* __restrict__ bpre, int NB){
  __shared__ int sm[1024];
  int t = threadIdx.x;
  int v = (t < NB) ? bsum[t] : 0;
  sm[t] = v; __syncthreads();
  #pragma unroll
  for (int off = 1; off < 1024; off <<= 1){
    int u = (t >= off) ? sm[t-off] : 0;
    __syncthreads();
    sm[t] += u;
    __syncthreads();
  }
  if (t < NB) bpre[t] = sm[t] - v;
  if (t == 1023) bpre[NB] = sm[1023];
}

__global__ __launch_bounds__(256) void scan3_kernel(int* __restrict__ offs,
    int* __restrict__ cursor, const int* __restrict__ bpre, int N, int NB){
  int i = blockIdx.x*256 + threadIdx.x;
  if (i < N){
    int v = offs[i] + bpre[blockIdx.x];
    offs[i] = v; cursor[i] = v;
  }
  if (i == 0) offs[N] = bpre[NB];
}

__global__ void scatter_kernel(const int* __restrict__ ei, int E, int N,
    int* __restrict__ cursor, int* __restrict__ csr_src, const int* __restrict__ flags){
  int i64 = flags[1];
  int i = blockIdx.x*blockDim.x + threadIdx.x;
  int Et = E + N;
  if (i < Et){
    int s, d;
    if (i < E){
      s = clampi(lde(ei, i, i64), 0, N-1);
      d = clampi(lde(ei, (size_t)E + i, i64), 0, N-1);
    } else { s = i - E; d = s; }
    int p = atomicAdd(&cursor[d], 1);
    csr_src[p] = s;
  }
}

// ---------------- B transpose: BT[col][k] = B[k][col], bf16 out (256x256) ----------------
__global__ __launch_bounds__(256) void btrans_kernel(const void* __restrict__ B,
    u16* __restrict__ BT, const int* __restrict__ flags){
  int f32 = flags[0];
  __shared__ u16 tile[64][65];
  int k0 = blockIdx.y*64, c0 = blockIdx.x*64;
  int r0 = threadIdx.x >> 6, c = threadIdx.x & 63;
  for (int r = r0; r < 64; r += 4)
    tile[r][c] = f32 ? f2bf(((const float*)B)[(size_t)(k0+r)*256 + c0 + c])
                     : ((const u16*)B)[(size_t)(k0+r)*256 + c0 + c];
  __syncthreads();
  for (int j = r0; j < 64; j += 4)
    BT[(size_t)(c0+j)*256 + k0 + c] = tile[c][j];
}

// ---------------- convert x (fp32 path only) to bf16 ----------------
__global__ __launch_bounds__(256) void convx_kernel(const void* __restrict__ x,
    u16* __restrict__ out, int N, const int* __restrict__ flags){
  if (!flags[0]) return;
  size_t i = (size_t)blockIdx.x*256 + threadIdx.x;
  if (i*8 >= (size_t)N*256) return;
  const float* xf = (const float*)x + i*8;
  float4 v0 = *(const float4*)xf, v1 = *(const float4*)(xf+4);
  us8 o = (us8){f2bf(v0.x),f2bf(v0.y),f2bf(v0.z),f2bf(v0.w),
                f2bf(v1.x),f2bf(v1.y),f2bf(v1.z),f2bf(v1.w)};
  *(us8*)(out + i*8) = o;
}

// ---------------- LDS-free MFMA GEMM: C[M,256] = A[M,256] @ B, A bf16, BT pre-transposed ----------------
// Block 256 thr = 4 waves (2x2), tile 128 rows x 64 cols. Fragments loaded directly from global.
__global__ __launch_bounds__(256) void gemm_mfma(const u16* __restrict__ A0,
    const u16* __restrict__ A1, const u16* __restrict__ BT, u16* __restrict__ C,
    int M, const int* __restrict__ flags){
  const u16* A = flags[0] ? A1 : A0;
  int tid = threadIdx.x;
  int wave = tid >> 6, lane = tid & 63;
  int wm = wave >> 1, wn = wave & 1;
  int l15 = lane & 15, l4 = lane >> 4;
  int row0 = blockIdx.y * 128, col0 = blockIdx.x * 64;
  int arow[4];
  #pragma unroll
  for (int mi = 0; mi < 4; mi++)
    arow[mi] = min(row0 + wm*64 + mi*16 + l15, M-1);
  const u16* Ab = A + 8*l4;
  const u16* Bb = BT + (size_t)(col0 + wn*32 + l15)*256 + 8*l4;
  f32x4 acc[4][2] = {};
  #pragma unroll 2
  for (int k0 = 0; k0 < 256; k0 += 32){
    short8v a[4], b[2];
    #pragma unroll
    for (int mi = 0; mi < 4; mi++)
      a[mi] = *(const short8v*)(Ab + (size_t)arow[mi]*256 + k0);
    #pragma unroll
    for (int ni = 0; ni < 2; ni++)
      b[ni] = *(const short8v*)(Bb + (size_t)ni*16*256 + k0);
    #pragma unroll
    for (int mi = 0; mi < 4; mi++)
      #pragma unroll
      for (int ni = 0; ni < 2; ni++)
        acc[mi][ni] = __builtin_amdgcn_mfma_f32_16x16x32_bf16(a[mi], b[ni], acc[mi][ni], 0, 0, 0);
  }
  #pragma unroll
  for (int mi = 0; mi < 4; mi++){
    #pragma unroll
    for (int ni = 0; ni < 2; ni++){
      #pragma unroll
      for (int r = 0; r < 4; r++){
        int row = row0 + wm*64 + mi*16 + l4*4 + r;
        int col = col0 + wn*32 + ni*16 + l15;
        if (row < M) C[(size_t)row*256 + col] = f2bf(acc[mi][ni][r]);
      }
    }
  }
}

// ---------------- per-node attention scores es/ed (4 nodes/block) ----------------
__global__ __launch_bounds__(256) void scores_kernel(const u16* __restrict__ h,
    const void* __restrict__ a_src, const void* __restrict__ a_dst,
    float* __restrict__ es, float* __restrict__ ed, int N, const int* __restrict__ flags){
  int f32 = flags[0];
  int ln = threadIdx.x & 63;
  int n = blockIdx.x*4 + (threadIdx.x >> 6);
  if (n >= N) return;
  int c0 = ln*4, hd = ln >> 4;
  ushort4 hv = *(const ushort4*)&h[(size_t)n*256 + c0];
  float4 s4 = ld4(a_src, c0, f32);
  float4 d4 = ld4(a_dst, c0, f32);
  float ps = bf2f(hv.x)*s4.x + bf2f(hv.y)*s4.y + bf2f(hv.z)*s4.z + bf2f(hv.w)*s4.w;
  float pd = bf2f(hv.x)*d4.x + bf2f(hv.y)*d4.y + bf2f(hv.z)*d4.z + bf2f(hv.w)*d4.w;
  #pragma unroll
  for (int off = 1; off < 16; off <<= 1){
    ps += __shfl_xor(ps, off, 64);
    pd += __shfl_xor(pd, off, 64);
  }
  if ((ln & 15) == 0){ es[(size_t)n*4 + hd] = ps; ed[(size_t)n*4 + hd] = pd; }
}

// ---------------- fused aggregation: wave per dst (round-4 winner, reverted) ----------------
__global__ __launch_bounds__(256) void agg_kernel(const u16* __restrict__ h,
    const int* __restrict__ csr_src, const int* __restrict__ offs,
    const float* __restrict__ es, const float* __restrict__ ed, int N,
    const void* __restrict__ bias, void* __restrict__ out, int do_relu, int outIsOutput,
    const int* __restrict__ flags){
  int f32in = flags[0];
  int of32  = outIsOutput ? flags[0] : 0;
  int ln = threadIdx.x & 63;
  int n = blockIdx.x*4 + (threadIdx.x >> 6);
  if (n >= N) return;
  int beg = offs[n], end = offs[n+1];
  int hd = ln >> 4, c0 = ln*4;
  float edn = ed[(size_t)n*4 + hd];
  float a0=0.f, a1=0.f, a2=0.f, a3=0.f, ws=0.f;
  int i = beg;
  for (; i + 8 <= end; i += 8){
    int s[8]; float x[8]; ushort4 hv[8];
    #pragma unroll
    for (int j = 0; j < 8; j++) s[j] = csr_src[i+j];
    #pragma unroll
    for (int j = 0; j < 8; j++) x[j] = es[(size_t)s[j]*4 + hd];
    #pragma unroll
    for (int j = 0; j < 8; j++) hv[j] = *(const ushort4*)&h[(size_t)s[j]*256 + c0];
    #pragma unroll
    for (int j = 0; j < 8; j++){
      float t = x[j] + edn; t = (t > 0.f) ? t : 0.2f*t; t = fminf(t, 60.f);
      float w = __expf(t);
      a0 += w*bf2f(hv[j].x); a1 += w*bf2f(hv[j].y);
      a2 += w*bf2f(hv[j].z); a3 += w*bf2f(hv[j].w);
      ws += w;
    }
  }
  for (; i + 4 <= end; i += 4){
    int s[4]; float x[4]; ushort4 hv[4];
    #pragma unroll
    for (int j = 0; j < 4; j++) s[j] = csr_src[i+j];
    #pragma unroll
    for (int j = 0; j < 4; j++) x[j] = es[(size_t)s[j]*4 + hd];
    #pragma unroll
    for (int j = 0; j < 4; j++) hv[j] = *(const ushort4*)&h[(size_t)s[j]*256 + c0];
    #pragma unroll
    for (int j = 0; j < 4; j++){
      float t = x[j] + edn; t = (t > 0.f) ? t : 0.2f*t; t = fminf(t, 60.f);
      float w = __expf(t);
      a0 += w*bf2f(hv[j].x); a1 += w*bf2f(hv[j].y);
      a2 += w*bf2f(hv[j].z); a3 += w*bf2f(hv[j].w);
      ws += w;
    }
  }
  for (; i < end; i++){
    int s = csr_src[i];
    float t = es[(size_t)s*4 + hd] + edn; t = (t > 0.f) ? t : 0.2f*t; t = fminf(t, 60.f);
    float w = __expf(t);
    ushort4 hv = *(const ushort4*)&h[(size_t)s*256 + c0];
    a0 += w*bf2f(hv.x); a1 += w*bf2f(hv.y);
    a2 += w*bf2f(hv.z); a3 += w*bf2f(hv.w);
    ws += w;
  }
  float inv = 1.f / (ws + 1e-16f);
  float4 bv = ld4(bias, c0, f32in);
  float4 ov = make_float4(a0*inv + bv.x, a1*inv + bv.y, a2*inv + bv.z, a3*inv + bv.w);
  if (do_relu){
    ov.x = fmaxf(ov.x, 0.f); ov.y = fmaxf(ov.y, 0.f);
    ov.z = fmaxf(ov.z, 0.f); ov.w = fmaxf(ov.w, 0.f);
  }
  st4(out, (size_t)n*256 + c0, ov, of32);
}

// ---------------- query part of classifier ----------------
__global__ void qpart_kernel(const void* __restrict__ query, const void* __restrict__ Wc,
    const void* __restrict__ bc, float* __restrict__ qp, int Q, const int* __restrict__ flags){
  int f32 = flags[0];
  int q = threadIdx.x >> 5, ln = threadIdx.x & 31;
  if (q >= Q) return;
  float s = 0.f;
  for (int j = ln; j < 256; j += 32) s += ld1(query, q*256 + j, f32) * ld1(Wc, j, f32);
  #pragma unroll
  for (int off = 16; off; off >>= 1) s += __shfl_down(s, off, 32);
  if (ln == 0) qp[q] = s + ld1(bc, 0, f32);
}

// ---------------- node scores ----------------
__global__ __launch_bounds__(256) void nscore_kernel(const void* __restrict__ dout,
    const void* __restrict__ Wc, const float* __restrict__ qp, int N, int Q,
    const int* __restrict__ flags){
  int f32 = flags[0];
  int wv = threadIdx.x >> 6, ln = threadIdx.x & 63;
  int n = blockIdx.x * 4 + wv;
  if (n >= N) return;
  float4 e4 = ld4(dout, (size_t)n*256 + ln*4, f32);
  float4 w4 = ld4(Wc, 256 + ln*4, f32);
  float v = e4.x*w4.x + e4.y*w4.y + e4.z*w4.z + e4.w*w4.w;
  #pragma unroll
  for (int off = 32; off; off >>= 1) v += __shfl_down(v, off, 64);
  v = __shfl(v, 0, 64);
  if (ln < Q) st1((void*)dout, (size_t)N*256 + (size_t)ln*N + n, qp[ln] + v, f32);
}

extern "C" void kernel_launch(void* const* d_in, const int* in_sizes, int n_in,
                              void* d_out, int out_size, void* d_ws, size_t ws_size,
                              hipStream_t stream){
  const void* x     = d_in[0];
  const int*  ei    = (const int*)d_in[1];
  const void* query = d_in[2];
  const void* W1    = d_in[3];
  const void* as1   = d_in[4];
  const void* ad1   = d_in[5];
  const void* b1    = d_in[6];
  const void* W2    = d_in[7];
  const void* as2   = d_in[8];
  const void* ad2   = d_in[9];
  const void* b2    = d_in[10];
  const void* Wc    = d_in[11];
  const void* bc    = d_in[12];

  int N = in_sizes[0] / 256;
  int E = in_sizes[1] / 2;
  int Q = in_sizes[2] / 256;
  int Et = E + N;
  int NB = (N + 255) / 256;

  char* p = (char*)d_ws;
  auto alloc = [&](size_t bytes)->char*{
    char* r = p; p += (bytes + 255) & ~(size_t)255; return r;
  };
  int*  flags   = (int*) alloc(256);
  u16*  bufA    = (u16*) alloc((size_t)N*256*2);   // h1 / h2
  u16*  bufB    = (u16*) alloc((size_t)N*256*2);   // conv(x) then relu(agg1) output
  float* es     = (float*)alloc((size_t)N*4*4);
  float* ed     = (float*)alloc((size_t)N*4*4);
  int*  deg     = (int*)  alloc((size_t)N*4);
  int*  offs    = (int*)  alloc((size_t)(N+1)*4);
  int*  cursor  = (int*)  alloc((size_t)N*4);
  int*  csr_src = (int*)  alloc((size_t)Et*4);
  int*  bsum    = (int*)  alloc((size_t)(NB+1)*4);
  int*  bpre    = (int*)  alloc((size_t)(NB+1)*4);
  u16*  BT1     = (u16*)  alloc(256*256*2);
  u16*  BT2     = (u16*)  alloc(256*256*2);
  float* qp     = (float*)alloc(64*4);

  const int thr = 256;
  detect_kernel<<<1, 256, 0, stream>>>((const u32*)x, ei, flags);

  hipMemsetAsync(deg, 0, (size_t)N*4, stream);
  count_kernel  <<<(Et + thr-1)/thr, thr, 0, stream>>>(ei, E, N, deg, flags);
  scan1_kernel  <<<NB, 256, 0, stream>>>(deg, offs, bsum, N);
  scan2_kernel  <<<1, 1024, 0, stream>>>(bsum, bpre, NB);
  scan3_kernel  <<<NB, 256, 0, stream>>>(offs, cursor, bpre, N, NB);
  scatter_kernel<<<(Et + thr-1)/thr, thr, 0, stream>>>(ei, E, N, cursor, csr_src, flags);

  dim3 tgrid(4, 4);
  dim3 ggrid(4, (N + 127)/128);
  dim3 ngrid((N + 3)/4);
  int cxblocks = (int)(((size_t)N*256/8 + 255) / 256);

  // prep: transpose weights, convert x if fp32
  btrans_kernel<<<tgrid, 256, 0, stream>>>(W1, BT1, flags);
  btrans_kernel<<<tgrid, 256, 0, stream>>>(W2, BT2, flags);
  convx_kernel <<<cxblocks, 256, 0, stream>>>(x, bufB, N, flags);

  // ---- layer 1 ----
  gemm_mfma    <<<ggrid, 256, 0, stream>>>((const u16*)x, bufB, BT1, bufA, N, flags);
  scores_kernel<<<ngrid, 256, 0, stream>>>(bufA, as1, ad1, es, ed, N, flags);
  agg_kernel   <<<ngrid, 256, 0, stream>>>(bufA, csr_src, offs, es, ed, N, b1, bufB, 1, 0, flags);
  // ---- layer 2 ----
  gemm_mfma    <<<ggrid, 256, 0, stream>>>(bufB, bufB, BT2, bufA, N, flags);
  scores_kernel<<<ngrid, 256, 0, stream>>>(bufA, as2, ad2, es, ed, N, flags);
  agg_kernel   <<<ngrid, 256, 0, stream>>>(bufA, csr_src, offs, es, ed, N, b2, d_out, 0, 1, flags);
  // ---- classifier head ----
  qpart_kernel <<<1, 256, 0, stream>>>(query, Wc, bc, qp, Q, flags);
  nscore_kernel<<<ngrid, 256, 0, stream>>>(d_out, Wc, qp, N, Q, flags);
}